// Round 4
// baseline (343.590 us; speedup 1.0000x reference)
//
#include <hip/hip_runtime.h>

#define O_DIM 256
#define C_DIM 256
#define P_DIM 96
#define KHW 51
#define NSP 2601      // 51*51
#define NT 64         // output-linear spatial tile
#define NTILES 41     // ceil(2601/64)
#define GROUPS 8      // contiguous tile-span groups per (o, c-half)
#define CSPLIT 2      // c dimension split across blocks
#define CB 128        // c rows per block
#define NF 8          // CB/16 column fragments
#define LDSV 104      // LDS row stride (bf16 elems)

typedef __attribute__((ext_vector_type(8))) short short8v;
typedef __attribute__((ext_vector_type(4))) float float4v;
typedef __attribute__((ext_vector_type(4), aligned(4))) float float4u;  // 4B-aligned vec store

__device__ __forceinline__ unsigned f2bf(float f) {
  union { float f; unsigned u; } v; v.f = f;
  return (v.u + 0x7FFFu + ((v.u >> 16) & 1u)) >> 16;  // RNE f32->bf16
}

__global__ __launch_bounds__(256) void smp_fused(
    const float* __restrict__ xg,   // (1,2,51,51)
    const float* __restrict__ wc,   // (O,P,2)
    const float* __restrict__ rad,  // (O,P,1,1)
    const float* __restrict__ wts,  // (O,C,P)
    float* __restrict__ out)        // (O,C,51,51) f32
{
  __shared__ unsigned short Vt[2][NT * LDSV];  // vals tiles [jl][p], double-buffered

  const int b = blockIdx.x;
  const int o = b >> 4;                 // /(CSPLIT*GROUPS)
  const int ch = (b >> 3) & 1;          // c-half
  const int grp = b & 7;
  const int tid = threadIdx.x;
  const int wave = tid >> 6;
  const int lane = tid & 63;
  const int row16 = lane & 15;
  const int kgrp = lane >> 4;

  // ---- B fragments (weights) in registers for whole kernel.
  // B[k=p][col=c]: lane holds col=(nf*16+row16), k=kgrp*8+j (8 consecutive p).
  short8v wfr[NF][3];
  {
    const float* Wo = wts + ((size_t)o * C_DIM + ch * CB) * P_DIM;
#pragma unroll
    for (int nf = 0; nf < NF; ++nf) {
      const float* src = Wo + (nf * 16 + row16) * P_DIM;
#pragma unroll
      for (int ks = 0; ks < 3; ++ks) {
        const float4 a = *(const float4*)(src + ks * 32 + kgrp * 8);
        const float4 c4 = *(const float4*)(src + ks * 32 + kgrp * 8 + 4);
        short8v f;
        f[0] = (short)f2bf(a.x);  f[1] = (short)f2bf(a.y);
        f[2] = (short)f2bf(a.z);  f[3] = (short)f2bf(a.w);
        f[4] = (short)f2bf(c4.x); f[5] = (short)f2bf(c4.y);
        f[6] = (short)f2bf(c4.z); f[7] = (short)f2bf(c4.w);
        wfr[nf][ks] = f;
      }
    }
  }

  // ---- per-thread point data (12 points), register-resident all kernel.
  // 8 threads per output location; division hoisted out of the tile loop.
  const int sp = tid & 7;
  const int jrow = tid >> 3;  // 0..31
  float py[12], px[12], pr[12];
  {
    const float* wp = wc + ((size_t)o * P_DIM + sp * 12) * 2;
    const float* rp = rad + (size_t)o * P_DIM + sp * 12;
#pragma unroll
    for (int k = 0; k < 12; ++k) {
      py[k] = wp[2 * k];
      px[k] = wp[2 * k + 1];
      pr[k] = 1.0f / rp[k];  // r=0.5 (pow2): d*pr bitwise == d/r, count stays exact
    }
  }

  const int t0 = (grp * NTILES) / GROUPS;
  const int t1 = ((grp + 1) * NTILES) / GROUPS;

  int bufi = 0;
  for (int tile = t0; tile < t1; ++tile, bufi ^= 1) {
    const int m0 = tile * NT;

    // ---- vals: 2 passes x 32 output rows; triangular basis + count-normalize
#pragma unroll
    for (int half = 0; half < 2; ++half) {
      int jl = m0 + half * 32 + jrow;      // output-linear index
      int jc = jl < NSP ? jl : NSP - 1;
      int i = jc / KHW;
      int jj = jc - i * KHW;
      int n = jj * KHW + (KHW - 1 - i);    // source spatial index
      float gy = xg[n];
      float gx = xg[NSP + n];
      float t[12];
      int cnt = 0;
#pragma unroll
      for (int k = 0; k < 12; ++k) {
        float d = fabsf(py[k] - gy) + fabsf(px[k] - gx);
        float v = 1.0f - d * pr[k];        // == 1 - d/r exactly (r pow2)
        v = v > 0.0f ? v : 0.0f;
        t[k] = v;
        cnt += (v != 0.0f);
      }
      cnt += __shfl_xor(cnt, 1);
      cnt += __shfl_xor(cnt, 2);
      cnt += __shfl_xor(cnt, 4);
      const float inv = __builtin_amdgcn_rcpf((float)cnt + 1e-6f);  // feeds bf16
      unsigned* dst = (unsigned*)(&Vt[bufi][(half * 32 + jrow) * LDSV + sp * 12]);
#pragma unroll
      for (int k = 0; k < 6; ++k)
        dst[k] = f2bf(t[2 * k] * inv) | (f2bf(t[2 * k + 1] * inv) << 16);
    }
    __syncthreads();

    // ---- GEMM: D[jl=16 per wave][c=128] = vals * W^T; A=vals, B=weights
    float4v acc[NF];
#pragma unroll
    for (int nf = 0; nf < NF; ++nf) acc[nf] = (float4v){0.f, 0.f, 0.f, 0.f};
#pragma unroll
    for (int ks = 0; ks < 3; ++ks) {
      short8v vfr = *(const short8v*)(
          &Vt[bufi][(wave * 16 + row16) * LDSV + ks * 32 + kgrp * 8]);
#pragma unroll
      for (int nf = 0; nf < NF; ++nf)
        acc[nf] = __builtin_amdgcn_mfma_f32_16x16x32_bf16(
            vfr, wfr[nf][ks], acc[nf], 0, 0, 0);
    }

    // ---- stores: C/D rows = jl (kgrp*4+reg) -> lane holds 4 CONSECUTIVE floats
    const int jb = m0 + wave * 16 + kgrp * 4;
    float* ob = out + ((size_t)o * C_DIM + ch * CB + row16) * NSP + jb;
    if (jb + 3 < NSP) {
#pragma unroll
      for (int nf = 0; nf < NF; ++nf) {
        float4u s = {acc[nf][0], acc[nf][1], acc[nf][2], acc[nf][3]};
        *(float4u*)(ob + (size_t)(nf * 16) * NSP) = s;
      }
    } else {
#pragma unroll
      for (int nf = 0; nf < NF; ++nf)
#pragma unroll
        for (int r = 0; r < 4; ++r)
          if (jb + r < NSP) ob[(size_t)(nf * 16) * NSP + r] = acc[nf][r];
    }
  }
}

extern "C" void kernel_launch(void* const* d_in, const int* in_sizes, int n_in,
                              void* d_out, int out_size, void* d_ws, size_t ws_size,
                              hipStream_t stream) {
  const float* xg  = (const float*)d_in[0];
  const float* wcp = (const float*)d_in[1];
  const float* rad = (const float*)d_in[2];
  const float* wts = (const float*)d_in[3];
  float* out = (float*)d_out;
  hipLaunchKernelGGL(smp_fused, dim3(O_DIM * CSPLIT * GROUPS), dim3(256), 0, stream,
                     xg, wcp, rad, wts, out);
}

// Round 5
// 313.572 us; speedup vs baseline: 1.0957x; 1.0957x over previous
//
#include <hip/hip_runtime.h>

#define O_DIM 256
#define C_DIM 256
#define P_DIM 96
#define KHW 51
#define NSP 2601      // 51*51
#define NT 64         // output-linear spatial tile
#define NTILES 41     // ceil(2601/64)
#define GROUPS 8      // contiguous tile-span groups per (o, c-quarter)
#define CSPLIT 4      // c dimension split across blocks
#define CB 64         // c rows per block
#define NF 4          // CB/16 column fragments
#define LDSV 104      // LDS row stride (bf16 elems)

typedef __attribute__((ext_vector_type(8))) short short8v;
typedef __attribute__((ext_vector_type(4))) float float4v;
typedef __attribute__((ext_vector_type(4), aligned(4))) float float4u;  // 4B-aligned vec store

__device__ __forceinline__ unsigned f2bf(float f) {
  union { float f; unsigned u; } v; v.f = f;
  return (v.u + 0x7FFFu + ((v.u >> 16) & 1u)) >> 16;  // RNE f32->bf16
}

__device__ __forceinline__ unsigned cvtpk(float lo, float hi) {
  unsigned r;
  asm("v_cvt_pk_bf16_f32 %0, %1, %2" : "=v"(r) : "v"(lo), "v"(hi));  // RNE pack
  return r;
}

__global__ __launch_bounds__(256, 4) void smp_fused(
    const float* __restrict__ xg,   // (1,2,51,51)
    const float* __restrict__ wc,   // (O,P,2)
    const float* __restrict__ rad,  // (O,P,1,1)
    const float* __restrict__ wts,  // (O,C,P)
    float* __restrict__ out)        // (O,C,51,51) f32
{
  __shared__ unsigned short Vt[2][NT * LDSV];  // vals tiles [jl][p], double-buffered

  const int b = blockIdx.x;
  const int o = b >> 5;                 // /(CSPLIT*GROUPS)
  const int cq = (b >> 3) & 3;          // c-quarter
  const int grp = b & 7;
  const int tid = threadIdx.x;
  const int wave = tid >> 6;
  const int lane = tid & 63;
  const int row16 = lane & 15;
  const int kgrp = lane >> 4;

  // ---- per-thread point data (12 points), register-resident all kernel.
  // 8 threads per output location; divisions hoisted out of the tile loop.
  const int sp = tid & 7;
  const int jrow = tid >> 3;  // 0..31
  float py[12], px[12], pr[12];
  {
    const float* wp = wc + ((size_t)o * P_DIM + sp * 12) * 2;
    const float* rp = rad + (size_t)o * P_DIM + sp * 12;
#pragma unroll
    for (int k = 0; k < 12; ++k) {
      py[k] = wp[2 * k];
      px[k] = wp[2 * k + 1];
      pr[k] = 1.0f / rp[k];  // r=0.5 (pow2): d*pr bitwise == d/r, count stays exact
    }
  }

  // ---- B fragments (weights, this block's 64 c-rows) in registers.
  // B[k=p][col=c]: lane holds col=(nf*16+row16), k=kgrp*8+j (8 consecutive p).
  short8v wfr[NF][3];
  {
    const float* Wo = wts + ((size_t)o * C_DIM + cq * CB) * P_DIM;
#pragma unroll
    for (int nf = 0; nf < NF; ++nf) {
      const float* src = Wo + (nf * 16 + row16) * P_DIM;
#pragma unroll
      for (int ks = 0; ks < 3; ++ks) {
        const float4 a = *(const float4*)(src + ks * 32 + kgrp * 8);
        const float4 c4 = *(const float4*)(src + ks * 32 + kgrp * 8 + 4);
        short8v f;
        f[0] = (short)f2bf(a.x);  f[1] = (short)f2bf(a.y);
        f[2] = (short)f2bf(a.z);  f[3] = (short)f2bf(a.w);
        f[4] = (short)f2bf(c4.x); f[5] = (short)f2bf(c4.y);
        f[6] = (short)f2bf(c4.z); f[7] = (short)f2bf(c4.w);
        wfr[nf][ks] = f;
      }
    }
  }

  const int t0 = (grp * NTILES) / GROUPS;
  const int t1 = ((grp + 1) * NTILES) / GROUPS;

  int bufi = 0;
  for (int tile = t0; tile < t1; ++tile, bufi ^= 1) {
    const int m0 = tile * NT;

    // ---- vals: 2 passes x 32 output rows; triangular basis + count-normalize
#pragma unroll
    for (int half = 0; half < 2; ++half) {
      int jl = m0 + half * 32 + jrow;      // output-linear index
      int jc = jl < NSP ? jl : NSP - 1;
      int i = jc / KHW;
      int jj = jc - i * KHW;
      int n = jj * KHW + (KHW - 1 - i);    // source spatial index
      float gy = xg[n];
      float gx = xg[NSP + n];
      float t[12];
      int cnt = 0;
#pragma unroll
      for (int k = 0; k < 12; ++k) {
        float d = fabsf(py[k] - gy) + fabsf(px[k] - gx);
        float v = 1.0f - d * pr[k];        // == 1 - d/r exactly (r pow2)
        v = v > 0.0f ? v : 0.0f;
        t[k] = v;
        cnt += (v != 0.0f);
      }
      cnt += __shfl_xor(cnt, 1);
      cnt += __shfl_xor(cnt, 2);
      cnt += __shfl_xor(cnt, 4);
      const float inv = __builtin_amdgcn_rcpf((float)cnt + 1e-6f);  // feeds bf16
      unsigned* dst = (unsigned*)(&Vt[bufi][(half * 32 + jrow) * LDSV + sp * 12]);
#pragma unroll
      for (int k = 0; k < 6; ++k)
        dst[k] = cvtpk(t[2 * k] * inv, t[2 * k + 1] * inv);
    }
    __syncthreads();

    // ---- GEMM: D[jl=16 per wave][c=64] = vals * W^T; A=vals(LDS), B=weights(reg)
    float4v acc[NF];
#pragma unroll
    for (int nf = 0; nf < NF; ++nf) acc[nf] = (float4v){0.f, 0.f, 0.f, 0.f};
#pragma unroll
    for (int ks = 0; ks < 3; ++ks) {
      short8v vfr = *(const short8v*)(
          &Vt[bufi][(wave * 16 + row16) * LDSV + ks * 32 + kgrp * 8]);
#pragma unroll
      for (int nf = 0; nf < NF; ++nf)
        acc[nf] = __builtin_amdgcn_mfma_f32_16x16x32_bf16(
            vfr, wfr[nf][ks], acc[nf], 0, 0, 0);
    }

    // ---- stores: C/D rows = jl (kgrp*4+reg) -> lane holds 4 CONSECUTIVE floats
    const int jb = m0 + wave * 16 + kgrp * 4;
    float* ob = out + ((size_t)o * C_DIM + cq * CB + row16) * NSP + jb;
    if (jb + 3 < NSP) {
#pragma unroll
      for (int nf = 0; nf < NF; ++nf) {
        float4u s = {acc[nf][0], acc[nf][1], acc[nf][2], acc[nf][3]};
        *(float4u*)(ob + (size_t)(nf * 16) * NSP) = s;
      }
    } else {
#pragma unroll
      for (int nf = 0; nf < NF; ++nf)
#pragma unroll
        for (int r = 0; r < 4; ++r)
          if (jb + r < NSP) ob[(size_t)(nf * 16) * NSP + r] = acc[nf][r];
    }
  }
}

extern "C" void kernel_launch(void* const* d_in, const int* in_sizes, int n_in,
                              void* d_out, int out_size, void* d_ws, size_t ws_size,
                              hipStream_t stream) {
  const float* xg  = (const float*)d_in[0];
  const float* wcp = (const float*)d_in[1];
  const float* rad = (const float*)d_in[2];
  const float* wts = (const float*)d_in[3];
  float* out = (float*)d_out;
  hipLaunchKernelGGL(smp_fused, dim3(O_DIM * CSPLIT * GROUPS), dim3(256), 0, stream,
                     xg, wcp, rad, wts, out);
}

// Round 6
// 238.452 us; speedup vs baseline: 1.4409x; 1.3150x over previous
//
#include <hip/hip_runtime.h>

#define O_DIM 256
#define C_DIM 256
#define P_DIM 96
#define KHW 51
#define NSP 2601      // 51*51
#define NT 128        // output-linear spatial tile
#define NTILES 21     // ceil(2601/128)
#define GROUPS 7      // 21/7 = 3 tiles per block, perfectly balanced
#define CSPLIT 2      // c dimension split across blocks
#define CB 128        // c rows per block
#define LDSV 104      // vals LDS row stride (bf16 elems)
#define BSTR 132      // bounce LDS row stride (f32 elems)

typedef __attribute__((ext_vector_type(8))) short short8v;
typedef __attribute__((ext_vector_type(4))) float float4v;
typedef __attribute__((ext_vector_type(4), aligned(16))) float float4a;

static __device__ __forceinline__ unsigned f2bf(float f) {
  union { float f; unsigned u; } v; v.f = f;
  return (v.u + 0x7FFFu + ((v.u >> 16) & 1u)) >> 16;  // RNE f32->bf16
}
static __device__ __forceinline__ unsigned cvtpk(float lo, float hi) {
  unsigned r;
  asm("v_cvt_pk_bf16_f32 %0, %1, %2" : "=v"(r) : "v"(lo), "v"(hi));  // RNE pack
  return r;
}

__global__ __launch_bounds__(256, 2) void smp_fused(
    const float* __restrict__ xg,   // (1,2,51,51)
    const float* __restrict__ wc,   // (O,P,2)
    const float* __restrict__ rad,  // (O,P,1,1)
    const float* __restrict__ wts,  // (O,C,P)
    float* __restrict__ out)        // (O,C,51,51) f32
{
  __shared__ __align__(16) unsigned short Vt[NT * LDSV];  // 26.6 KB vals [jl][p]
  __shared__ __align__(16) float Bf[4 * 16 * BSTR];       // 33.8 KB wave-private bounce

  const int b = blockIdx.x;
  const int o = b / (CSPLIT * GROUPS);
  const int rr = b - o * (CSPLIT * GROUPS);
  const int ch = rr / GROUPS;
  const int grp = rr - ch * GROUPS;
  const int tid = threadIdx.x;
  const int wave = tid >> 6;
  const int lane = tid & 63;
  const int row16 = lane & 15;
  const int kgrp = lane >> 4;

  // ---- per-thread point data (12 points) in registers; divides hoisted.
  const int sp = tid & 7;
  const int jrow = tid >> 3;  // 0..31
  float py[12], px[12], pr[12];
  {
    const float* wp = wc + ((size_t)o * P_DIM + sp * 12) * 2;
    const float* rp = rad + (size_t)o * P_DIM + sp * 12;
#pragma unroll
    for (int k = 0; k < 12; ++k) {
      py[k] = wp[2 * k];
      px[k] = wp[2 * k + 1];
      pr[k] = 1.0f / rp[k];  // r=0.5 (pow2): d*pr bitwise == d/r, count stays exact
    }
  }

  // ---- A fragments (weights): wave owns c rows ch*CB + wave*32 + mf*16 + row16
  short8v wfr[2][3];
  {
    const float* Wo = wts + ((size_t)o * C_DIM + ch * CB + wave * 32) * P_DIM;
#pragma unroll
    for (int mf = 0; mf < 2; ++mf) {
      const float* src = Wo + (mf * 16 + row16) * P_DIM;
#pragma unroll
      for (int ks = 0; ks < 3; ++ks) {
        const float4 a = *(const float4*)(src + ks * 32 + kgrp * 8);
        const float4 c4 = *(const float4*)(src + ks * 32 + kgrp * 8 + 4);
        short8v f;
        f[0] = (short)f2bf(a.x);  f[1] = (short)f2bf(a.y);
        f[2] = (short)f2bf(a.z);  f[3] = (short)f2bf(a.w);
        f[4] = (short)f2bf(c4.x); f[5] = (short)f2bf(c4.y);
        f[6] = (short)f2bf(c4.z); f[7] = (short)f2bf(c4.w);
        wfr[mf][ks] = f;
      }
    }
  }

  float* slice = &Bf[wave * 16 * BSTR];
  const int cl2 = lane >> 5;          // 0/1: which of 2 c-rows per store
  const int jo = (lane & 31) * 4;     // float offset within 128-jl run

  const int t0 = grp * 3;
  const int t1 = t0 + 3;

  for (int tile = t0; tile < t1; ++tile) {
    const int m0 = tile * NT;

    // ---- vals: 4 passes x 32 output rows; triangular basis + count-normalize
#pragma unroll
    for (int q = 0; q < 4; ++q) {
      int jl = m0 + q * 32 + jrow;         // output-linear index
      int jc = jl < NSP ? jl : NSP - 1;
      int i = jc / KHW;
      int jj = jc - i * KHW;
      int n = jj * KHW + (KHW - 1 - i);    // source spatial index
      float gy = xg[n];
      float gx = xg[NSP + n];
      float t[12];
      int cnt = 0;
#pragma unroll
      for (int k = 0; k < 12; ++k) {
        float d = fabsf(py[k] - gy) + fabsf(px[k] - gx);
        float v = 1.0f - d * pr[k];        // == 1 - d/r exactly (r pow2)
        v = v > 0.0f ? v : 0.0f;
        t[k] = v;
        cnt += (v != 0.0f);
      }
      cnt += __shfl_xor(cnt, 1);
      cnt += __shfl_xor(cnt, 2);
      cnt += __shfl_xor(cnt, 4);
      const float inv = __builtin_amdgcn_rcpf((float)cnt + 1e-6f);  // feeds bf16
      unsigned* dst = (unsigned*)(&Vt[(q * 32 + jrow) * LDSV + sp * 12]);
#pragma unroll
      for (int k = 0; k < 6; ++k)
        dst[k] = cvtpk(t[2 * k] * inv, t[2 * k + 1] * inv);
    }
    __syncthreads();   // vals ready

    // ---- GEMM: D[c=32 per wave][jl=128] ; A=weights(reg), B=vals(LDS)
    float4v acc[2][8];
#pragma unroll
    for (int mf = 0; mf < 2; ++mf)
#pragma unroll
      for (int f = 0; f < 8; ++f)
        acc[mf][f] = (float4v){0.f, 0.f, 0.f, 0.f};

#pragma unroll
    for (int ks = 0; ks < 3; ++ks) {
      short8v bfr[8];
#pragma unroll
      for (int f = 0; f < 8; ++f)
        bfr[f] = *(const short8v*)(&Vt[(f * 16 + row16) * LDSV + ks * 32 + kgrp * 8]);
#pragma unroll
      for (int mf = 0; mf < 2; ++mf)
#pragma unroll
        for (int f = 0; f < 8; ++f)
          acc[mf][f] = __builtin_amdgcn_mfma_f32_16x16x32_bf16(
              wfr[mf][ks], bfr[f], acc[mf][f], 0, 0, 0);
    }
    __syncthreads();   // Vt consumed; next tile's vals may overwrite

    // ---- wave-private LDS bounce -> fully-contiguous 512B-per-row stores
#pragma unroll
    for (int mf = 0; mf < 2; ++mf) {
      // scatter acc (16c x 128jl) into slice[c][jl]
#pragma unroll
      for (int f = 0; f < 8; ++f)
#pragma unroll
        for (int r = 0; r < 4; ++r)
          slice[(kgrp * 4 + r) * BSTR + f * 16 + row16] = acc[mf][f][r];
      // read back row-linear, store 1KB per instruction (2 rows x 512B)
      const size_t cbase = (size_t)o * C_DIM + ch * CB + wave * 32 + mf * 16;
      if (m0 + NT <= NSP) {
#pragma unroll
        for (int s = 0; s < 8; ++s) {
          int cl = s * 2 + cl2;
          float4a v = *(const float4a*)(&slice[cl * BSTR + jo]);
          *(float4a*)(out + (cbase + cl) * NSP + m0 + jo) = v;
        }
      } else {
        int rem = NSP - m0;   // 41 on the last tile
#pragma unroll
        for (int s = 0; s < 8; ++s) {
          int cl = s * 2 + cl2;
          float4a v = *(const float4a*)(&slice[cl * BSTR + jo]);
          float* gp = out + (cbase + cl) * NSP + m0 + jo;
          if (jo + 3 < rem) {
            *(float4a*)gp = v;
          } else {
#pragma unroll
            for (int r = 0; r < 4; ++r)
              if (jo + r < rem) gp[r] = v[r];
          }
        }
      }
    }
  }
}

extern "C" void kernel_launch(void* const* d_in, const int* in_sizes, int n_in,
                              void* d_out, int out_size, void* d_ws, size_t ws_size,
                              hipStream_t stream) {
  const float* xg  = (const float*)d_in[0];
  const float* wcp = (const float*)d_in[1];
  const float* rad = (const float*)d_in[2];
  const float* wts = (const float*)d_in[3];
  float* out = (float*)d_out;
  hipLaunchKernelGGL(smp_fused, dim3(O_DIM * CSPLIT * GROUPS), dim3(256), 0, stream,
                     xg, wcp, rad, wts, out);
}

// Round 7
// 235.602 us; speedup vs baseline: 1.4583x; 1.0121x over previous
//
#include <hip/hip_runtime.h>

#define O_DIM 256
#define C_DIM 256
#define P_DIM 96
#define KHW 51
#define NSP 2601      // 51*51
#define NT 128        // output-linear spatial tile
#define NTILES 21     // 20 full + 41-tail
#define CSPLIT 4      // c dimension split across blocks
#define CB 64         // c rows per block (16 per wave)
#define LDSV 104      // vals LDS row stride (bf16 elems)
#define BSTR 164      // bounce slice row stride (f32); banks: 164%32=4 -> <=2-way

typedef __attribute__((ext_vector_type(8))) short short8v;
typedef __attribute__((ext_vector_type(4))) float float4v;
typedef __attribute__((ext_vector_type(4), aligned(16))) float float4a;

static __device__ __forceinline__ unsigned f2bf(float f) {
  union { float f; unsigned u; } v; v.f = f;
  return (v.u + 0x7FFFu + ((v.u >> 16) & 1u)) >> 16;  // RNE f32->bf16
}
static __device__ __forceinline__ unsigned cvtpk(float lo, float hi) {
  unsigned r;
  asm("v_cvt_pk_bf16_f32 %0, %1, %2" : "=v"(r) : "v"(lo), "v"(hi));  // RNE pack
  return r;
}

__global__ __launch_bounds__(256, 2) void smp_fused(
    const float* __restrict__ xg,   // (1,2,51,51)
    const float* __restrict__ wc,   // (O,P,2)
    const float* __restrict__ rad,  // (O,P,1,1)
    const float* __restrict__ wts,  // (O,C,P)
    float* __restrict__ out)        // (O,C,51,51) f32
{
  __shared__ __align__(16) unsigned short Vt[NT * LDSV];  // 26.6 KB vals [jl][p]
  __shared__ __align__(16) float Bf[4 * 16 * BSTR];       // 42 KB wave-private slices

  const int b = blockIdx.x;
  const int o = b >> 2;
  const int cq = b & 3;
  const int tid = threadIdx.x;
  const int wave = tid >> 6;
  const int lane = tid & 63;
  const int row16 = lane & 15;
  const int kgrp = lane >> 4;

  // ---- per-thread point data (12 points) in registers; divides hoisted.
  const int sp = tid & 7;
  const int jrow = tid >> 3;  // 0..31
  float py[12], px[12], pr[12];
  {
    const float* wp = wc + ((size_t)o * P_DIM + sp * 12) * 2;
    const float* rp = rad + (size_t)o * P_DIM + sp * 12;
#pragma unroll
    for (int k = 0; k < 12; ++k) {
      py[k] = wp[2 * k];
      px[k] = wp[2 * k + 1];
      pr[k] = 1.0f / rp[k];  // r=0.5 (pow2): d*pr bitwise == d/r, count stays exact
    }
  }

  // ---- A fragments (weights): wave owns 16 c-rows: cq*CB + wave*16 + row16
  const int cw = cq * CB + wave * 16;   // wave's first c-row
  short8v wfr[3];
  {
    const float* src = wts + ((size_t)o * C_DIM + cw + row16) * P_DIM;
#pragma unroll
    for (int ks = 0; ks < 3; ++ks) {
      const float4 a4 = *(const float4*)(src + ks * 32 + kgrp * 8);
      const float4 c4 = *(const float4*)(src + ks * 32 + kgrp * 8 + 4);
      short8v f;
      f[0] = (short)f2bf(a4.x); f[1] = (short)f2bf(a4.y);
      f[2] = (short)f2bf(a4.z); f[3] = (short)f2bf(a4.w);
      f[4] = (short)f2bf(c4.x); f[5] = (short)f2bf(c4.y);
      f[6] = (short)f2bf(c4.z); f[7] = (short)f2bf(c4.w);
      wfr[ks] = f;
    }
  }

  float* slice = &Bf[wave * 16 * BSTR];
  const int cl2 = lane >> 5;          // 0/1: which of 2 c-rows per store pair
  const int jo = (lane & 31) * 4;     // float offset within 128-float window
  const int hrow = lane >> 2;         // head/leftover lane mapping: row 0..15
  const int hk = lane & 3;

  // per-lane alignment shifts for the scatter rows (row = kgrp*4 + r)
  int sS[4];
#pragma unroll
  for (int r = 0; r < 4; ++r) {
    int c_sc = cw + kgrp * 4 + r;
    sS[r] = 32 - ((-(9 * c_sc)) & 31);   // 1..32
  }

  for (int t = 0; t < NTILES; ++t) {
    const int m0 = t * NT;

    // ---- vals: 4 passes x 32 output rows; triangular basis + count-normalize
#pragma unroll
    for (int q = 0; q < 4; ++q) {
      int jl = m0 + q * 32 + jrow;         // output-linear index
      int jc = jl < NSP ? jl : NSP - 1;
      int i = jc / KHW;
      int jj = jc - i * KHW;
      int n = jj * KHW + (KHW - 1 - i);    // source spatial index
      float gy = xg[n];
      float gx = xg[NSP + n];
      float t12[12];
      int cnt = 0;
#pragma unroll
      for (int k = 0; k < 12; ++k) {
        float d = fabsf(py[k] - gy) + fabsf(px[k] - gx);
        float v = 1.0f - d * pr[k];        // == 1 - d/r exactly (r pow2)
        v = v > 0.0f ? v : 0.0f;
        t12[k] = v;
        cnt += (v != 0.0f);
      }
      cnt += __shfl_xor(cnt, 1);
      cnt += __shfl_xor(cnt, 2);
      cnt += __shfl_xor(cnt, 4);
      const float inv = __builtin_amdgcn_rcpf((float)cnt + 1e-6f);  // feeds bf16
      unsigned* dst = (unsigned*)(&Vt[(q * 32 + jrow) * LDSV + sp * 12]);
#pragma unroll
      for (int k = 0; k < 6; ++k)
        dst[k] = cvtpk(t12[2 * k] * inv, t12[2 * k + 1] * inv);
    }
    __syncthreads();   // vals ready

    // ---- GEMM: D[c=16 per wave][jl=128]; A=weights(reg), B=vals(LDS)
    float4v acc[8];
#pragma unroll
    for (int f = 0; f < 8; ++f) acc[f] = (float4v){0.f, 0.f, 0.f, 0.f};
#pragma unroll
    for (int ks = 0; ks < 3; ++ks) {
      short8v bfr[8];
#pragma unroll
      for (int f = 0; f < 8; ++f)
        bfr[f] = *(const short8v*)(&Vt[(f * 16 + row16) * LDSV + ks * 32 + kgrp * 8]);
#pragma unroll
      for (int f = 0; f < 8; ++f)
        acc[f] = __builtin_amdgcn_mfma_f32_16x16x32_bf16(
            wfr[ks], bfr[f], acc[f], 0, 0, 0);
    }
    __syncthreads();   // Vt consumed; next tile's vals may overwrite

    // ---- scatter into wave-private slice at per-row alignment shift s
    // C/D: jl-offset = f*16 + row16 (col), c-offset = kgrp*4 + r (row)
#pragma unroll
    for (int f = 0; f < 8; ++f)
#pragma unroll
      for (int r = 0; r < 4; ++r)
        slice[(kgrp * 4 + r) * BSTR + sS[r] + f * 16 + row16] = acc[f][r];

    // ---- one-time head store [0, a) per row (t==0)
    if (t == 0) {
      const int c_row = cw + hrow;
      const int a = (-(9 * c_row)) & 31;
      const int s = 32 - a;
      float* rb = out + ((size_t)o * C_DIM + c_row) * NSP;
#pragma unroll
      for (int i = 0; i < 8; ++i) {
        int j = hk + 4 * i;
        if (j < a) rb[j] = slice[hrow * BSTR + s + j];
      }
    }

    // ---- aligned store pass: full 128B lines only; jl window [128t - s, ...)
#pragma unroll
    for (int sq = 0; sq < 8; ++sq) {
      const int cl = sq * 2 + cl2;
      const int c_row = cw + cl;
      const int s = 32 - ((-(9 * c_row)) & 31);
      float* rb = out + ((size_t)o * C_DIM + c_row) * NSP;
      const float4a v = *(const float4a*)(&slice[cl * BSTR + jo]);
      if (t == 0) {
        if (jo >= 32) *(float4a*)(rb + (jo - s)) = v;
      } else if (t == NTILES - 1) {
        const int lim = s + (NSP - (NTILES - 1) * NT);   // s + 41
        const int base = (NTILES - 1) * NT - s;
        if (jo + 4 <= lim) {
          *(float4a*)(rb + base + jo) = v;
        } else if (jo < lim) {
#pragma unroll
          for (int r2 = 0; r2 < 4; ++r2)
            if (jo + r2 < lim) rb[base + jo + r2] = v[r2];
        }
      } else {
        *(float4a*)(rb + (t * NT - s) + jo) = v;
      }
    }

    // ---- carry leftover cols [128, 128+s) -> [0, s) for next tile
    if (t < NTILES - 1) {
      const int c_row = cw + hrow;
      const int s = 32 - ((-(9 * c_row)) & 31);
#pragma unroll
      for (int i = 0; i < 8; ++i) {
        int j = hk + 4 * i;
        if (j < s) slice[hrow * BSTR + j] = slice[hrow * BSTR + 128 + j];
      }
    }
  }
}

extern "C" void kernel_launch(void* const* d_in, const int* in_sizes, int n_in,
                              void* d_out, int out_size, void* d_ws, size_t ws_size,
                              hipStream_t stream) {
  const float* xg  = (const float*)d_in[0];
  const float* wcp = (const float*)d_in[1];
  const float* rad = (const float*)d_in[2];
  const float* wts = (const float*)d_in[3];
  float* out = (float*)d_out;
  hipLaunchKernelGGL(smp_fused, dim3(O_DIM * CSPLIT), dim3(256), 0, stream,
                     xg, wcp, rad, wts, out);
}

// Round 8
// 234.535 us; speedup vs baseline: 1.4650x; 1.0046x over previous
//
#include <hip/hip_runtime.h>

#define O_DIM 256
#define C_DIM 256
#define P_DIM 96
#define KHW 51
#define NSP 2601       // 51*51
#define NST 41         // supertiles of 64 jl (40 full + 41-tail)
#define CSPLIT 4
#define CB 64          // c rows per block
#define PITCH 68       // slice row stride (f32): 16B-aligned rows, 2-way-max scatter banks

typedef __attribute__((ext_vector_type(8))) short short8v;
typedef __attribute__((ext_vector_type(4))) float float4v;
typedef __attribute__((ext_vector_type(4), aligned(16))) float float4a;
typedef __attribute__((ext_vector_type(4), aligned(4))) float float4u;

static __device__ __forceinline__ unsigned f2bf(float f) {
  union { float f; unsigned u; } v; v.f = f;
  return (v.u + 0x7FFFu + ((v.u >> 16) & 1u)) >> 16;  // RNE f32->bf16
}
static __device__ __forceinline__ unsigned cvtpk(float lo, float hi) {
  unsigned r;
  asm("v_cvt_pk_bf16_f32 %0, %1, %2" : "=v"(r) : "v"(lo), "v"(hi));  // RNE pack
  return r;
}

__global__ __launch_bounds__(256, 4) void smp_fused(
    const float* __restrict__ xg,   // (1,2,51,51)
    const float* __restrict__ wc,   // (O,P,2)
    const float* __restrict__ rad,  // (O,P,1,1)
    const float* __restrict__ wts,  // (O,C,P)
    float* __restrict__ out)        // (O,C,51,51) f32
{
  __shared__ float Ylds[56];                       // ys[0..50]
  __shared__ float pyL[96], pxL[96], prL[96];      // point data (SoA)
  __shared__ __align__(16) float Sl[2][64 * PITCH];// 34.8 KB double-buffered slice

  const int b = blockIdx.x;
  const int o = b >> 2;
  const int cq = b & 3;
  const int tid = threadIdx.x;
  const int wave = tid >> 6;
  const int lane = tid & 63;
  const int row16 = lane & 15;
  const int kgrp = lane >> 4;

  // ---- one-time staging: ys vector + point SoA (exact input values)
  if (tid < 51) Ylds[tid] = xg[tid * KHW];          // ys[k] = x[0,0,k,0]
  if (tid < 96) {
    pyL[tid] = wc[((size_t)o * P_DIM + tid) * 2];
    pxL[tid] = wc[((size_t)o * P_DIM + tid) * 2 + 1];
    prL[tid] = 1.0f / rad[(size_t)o * P_DIM + tid]; // r=0.5 pow2: d*pr == d/r exactly
  }

  // ---- A fragments (weights): block's 64 c-rows, in registers.
  // A[row=c][k=p]: lane holds row=row16 (c = cq*64 + mf*16 + row16), k=kgrp*8+j.
  short8v wfr[4][3];
  {
    const float* Wo = wts + ((size_t)o * C_DIM + cq * CB) * P_DIM;
#pragma unroll
    for (int mf = 0; mf < 4; ++mf) {
      const float* src = Wo + (mf * 16 + row16) * P_DIM;
#pragma unroll
      for (int ks = 0; ks < 3; ++ks) {
        const float4 a4 = *(const float4*)(src + ks * 32 + kgrp * 8);
        const float4 c4 = *(const float4*)(src + ks * 32 + kgrp * 8 + 4);
        short8v f;
        f[0] = (short)f2bf(a4.x); f[1] = (short)f2bf(a4.y);
        f[2] = (short)f2bf(a4.z); f[3] = (short)f2bf(a4.w);
        f[4] = (short)f2bf(c4.x); f[5] = (short)f2bf(c4.y);
        f[6] = (short)f2bf(c4.z); f[7] = (short)f2bf(c4.w);
        wfr[mf][ks] = f;
      }
    }
  }
  __syncthreads();   // staging visible

  const int jb = wave * 16 + row16;     // lane's jl offset within supertile
  const int q = tid & 15;               // store-pass col group (16 x 16B = 256B/row)
  const int h = tid >> 4;               // store-pass row group
  const size_t obase = ((size_t)o * C_DIM + cq * CB) * NSP;

  for (int st = 0; st < NST; ++st) {
    // ---- vals (B-fragments born in-lane) + MFMA, zero LDS staging
    const int jl = st * 64 + jb;
    const int jc = jl < NSP ? jl : NSP - 1;
    const int i = jc / KHW;
    const int jj = jc - i * KHW;
    const float gy = Ylds[jj];
    const float gx = Ylds[50 - i];

    float4v acc[4];
#pragma unroll
    for (int mf = 0; mf < 4; ++mf) acc[mf] = (float4v){0.f, 0.f, 0.f, 0.f};

    int cnt = 0;
#pragma unroll
    for (int ks = 0; ks < 3; ++ks) {
      const int pb = ks * 32 + kgrp * 8;
      const float4a py0 = *(const float4a*)&pyL[pb];
      const float4a py1 = *(const float4a*)&pyL[pb + 4];
      const float4a px0 = *(const float4a*)&pxL[pb];
      const float4a px1 = *(const float4a*)&pxL[pb + 4];
      const float4a pr0 = *(const float4a*)&prL[pb];
      const float4a pr1 = *(const float4a*)&prL[pb + 4];
      float s[8], v[8];
#pragma unroll
      for (int j = 0; j < 4; ++j) {
        s[j]     = fmaf(fabsf(py0[j] - gy) + fabsf(px0[j] - gx), -pr0[j], 1.0f);
        s[j + 4] = fmaf(fabsf(py1[j] - gy) + fabsf(px1[j] - gx), -pr1[j], 1.0f);
      }
#pragma unroll
      for (int j = 0; j < 8; ++j) {
        v[j] = s[j] > 0.0f ? s[j] : 0.0f;
        cnt += (s[j] > 0.0f);
      }
      union { unsigned u[4]; short8v sv; } bfr;
#pragma unroll
      for (int jp = 0; jp < 4; ++jp) bfr.u[jp] = cvtpk(v[2 * jp], v[2 * jp + 1]);
#pragma unroll
      for (int mf = 0; mf < 4; ++mf)
        acc[mf] = __builtin_amdgcn_mfma_f32_16x16x32_bf16(
            wfr[mf][ks], bfr.sv, acc[mf], 0, 0, 0);
    }
    // count over all 96 p: 4 lanes per jl (kgrp 0..3)
    cnt += __shfl_xor(cnt, 16);
    cnt += __shfl_xor(cnt, 32);
    const float inv = __builtin_amdgcn_rcpf((float)cnt + 1e-6f);

    // ---- scatter acc*inv into slice: D row = kgrp*4+r (c-local), col = lane's jl
    float* sl = &Sl[st & 1][0];
#pragma unroll
    for (int mf = 0; mf < 4; ++mf)
#pragma unroll
      for (int r = 0; r < 4; ++r)
        sl[(mf * 16 + kgrp * 4 + r) * PITCH + jb] = acc[mf][r] * inv;

    __syncthreads();   // slice[st&1] complete (also fences store-reads of st-2's reuse)

    // ---- store pass: 64 rows x 256B contiguous runs; drains under next compute
    if (st < NST - 1) {
#pragma unroll
      for (int i2 = 0; i2 < 4; ++i2) {
        const int row = h * 4 + i2;
        const float4a vv = *(const float4a*)&sl[row * PITCH + q * 4];
        float4u sv = {vv[0], vv[1], vv[2], vv[3]};
        *(float4u*)(out + obase + (size_t)row * NSP + st * 64 + q * 4) = sv;
      }
    } else {
      const int rem = NSP - (NST - 1) * 64;   // 41
#pragma unroll
      for (int i2 = 0; i2 < 4; ++i2) {
        const int row = h * 4 + i2;
        const float4a vv = *(const float4a*)&sl[row * PITCH + q * 4];
        float* gp = out + obase + (size_t)row * NSP + st * 64 + q * 4;
        if (q * 4 + 3 < rem) {
          float4u sv = {vv[0], vv[1], vv[2], vv[3]};
          *(float4u*)gp = sv;
        } else if (q * 4 < rem) {
#pragma unroll
          for (int r2 = 0; r2 < 4; ++r2)
            if (q * 4 + r2 < rem) gp[r2] = vv[r2];
        }
      }
    }
  }
}

extern "C" void kernel_launch(void* const* d_in, const int* in_sizes, int n_in,
                              void* d_out, int out_size, void* d_ws, size_t ws_size,
                              hipStream_t stream) {
  const float* xg  = (const float*)d_in[0];
  const float* wcp = (const float*)d_in[1];
  const float* rad = (const float*)d_in[2];
  const float* wts = (const float*)d_in[3];
  float* out = (float*)d_out;
  hipLaunchKernelGGL(smp_fused, dim3(O_DIM * CSPLIT), dim3(256), 0, stream,
                     xg, wcp, rad, wts, out);
}